// Round 10
// baseline (1491.743 us; speedup 1.0000x reference)
//
#include <hip/hip_runtime.h>
#include <math.h>

#define BN 2048
#define DN 8
#define NEGW -1e9f
#define TPB 256            // threads per block (4 waves)
#define RPB 64             // rows per block (each thread owns 4 rows)
#define RS 16              // row-slots (t & 15); rows rs, rs+16, rs+32, rs+48
#define JSPLIT 16          // j-chunks; jc = t>>4 (quarter-wave uniform broadcast)
#define SLOTS (BN/2)       // logical float4 slots (2 j per slot)
#define SPC (SLOTS/JSPLIT) // 64 slots = 128 j per chunk
#define CPAD 65            // physical chunk stride in slots (+1 pad)

typedef float f2 __attribute__((ext_vector_type(2)));

static __device__ __forceinline__ float wave_reduce_sum(float v){
  #pragma unroll
  for (int off = 32; off > 0; off >>= 1) v += __shfl_xor(v, off, 64);
  return v;
}

// Packed exp2 on the MAIN VALU pipe (v_pk_* ops), for e <= 0.
// Round-to-int magic split + degree-6 Taylor/Horner + exponent reassembly.
// Rel err ~1e-7; clamp at -126 maps masked (-1e9) entries to ~1e-38 ~ 0.
static __device__ __forceinline__ f2 exp2_poly(f2 e){
  e = __builtin_elementwise_max(e, (f2){-126.f, -126.f});
  const float BIG = 12582912.f;              // 0x1.8p23, RTN rounds to int
  f2 t = e + (f2){BIG, BIG};
  f2 f = e - (t - (f2){BIG, BIG});           // f in [-0.5, 0.5]
  f2 p = (f2){1.5403530e-4f, 1.5403530e-4f}; // ln2^6/720
  p = __builtin_elementwise_fma(p, f, (f2){1.3333558e-3f, 1.3333558e-3f});
  p = __builtin_elementwise_fma(p, f, (f2){9.6181291e-3f, 9.6181291e-3f});
  p = __builtin_elementwise_fma(p, f, (f2){5.5504109e-2f, 5.5504109e-2f});
  p = __builtin_elementwise_fma(p, f, (f2){2.4022651e-1f, 2.4022651e-1f});
  p = __builtin_elementwise_fma(p, f, (f2){6.9314718e-1f, 6.9314718e-1f});
  p = __builtin_elementwise_fma(p, f, (f2){1.f, 1.f});
  union { float fv; unsigned uv; } t0, t1, p0, p1;
  t0.fv = t.x; t1.fv = t.y; p0.fv = p.x; p1.fv = p.y;
  p0.uv += t0.uv << 23;                      // *= 2^n (n in low bits of t)
  p1.uv += t1.uv << 23;
  return (f2){p0.fv, p1.fv};
}
static __device__ __forceinline__ f2 exp2_hw(f2 e){
  return (f2){__builtin_amdgcn_exp2f(e.x), __builtin_amdgcn_exp2f(e.y)};
}

// Transpose inputs into per-dim columns, build masked y, counts, logw.
__global__ void setup_kernel(const float* __restrict__ pred, const float* __restrict__ targ,
                             float* __restrict__ xcol, float* __restrict__ ycol,
                             float* __restrict__ logw, float* __restrict__ counts){
  int d = blockIdx.x;          // 8 blocks
  int t = threadIdx.x;         // 256 threads
  int lane = t & 63, wave = t >> 6;
  float mk[BN/256];
  float c = 0.f;
  for (int k = 0; k < BN/256; k++){
    int i = t + k*256;
    float tv = targ[i*DN + d];
    bool m = !(tv != tv);      // !isnan
    mk[k] = m ? 1.f : 0.f;
    c += mk[k];
    ycol[d*BN + i] = m ? tv : 0.f;
    xcol[d*BN + i] = pred[i*DN + d];
  }
  __shared__ float sh[4];
  __shared__ float logn_sh;
  float cw = wave_reduce_sum(c);
  if (lane == 0) sh[wave] = cw;
  __syncthreads();
  if (t == 0){
    float tot = sh[0] + sh[1] + sh[2] + sh[3];
    counts[d] = tot;
    logn_sh = logf(fmaxf(tot, 1.f));
  }
  __syncthreads();
  float ln = logn_sh;
  for (int k = 0; k < BN/256; k++){
    int i = t + k*256;
    logw[d*BN + i] = (mk[k] > 0.f) ? -ln : NEGW;
  }
}

// One Sinkhorn phase. Round-10: HYBRID exp - rounds 5-9 post-mortem shows
// step time pinned ~19-21us across all LDS/ILP/occupancy configs; the only
// invariant is the exp2 count -> transcendental-pipe-bound (v_exp_f32
// ~4 lanes/cyc: 134M exps/step = 14.5us/step on trans alone). Split the
// exp work: rows 0-1 use HW v_exp_f32 (trans pipe), rows 2-3 use packed
// polynomial exp2 (main VALU pipe) -> both pipes run concurrently.
__global__ __launch_bounds__(TPB) void sink_step(
      const float* __restrict__ xcol, const float* __restrict__ ycol,
      const float* __restrict__ logw,
      const float* __restrict__ dold, float* __restrict__ dnew,
      float eps, float inv_eps, int mode){
  const float L2E = 1.44269504088896340736f;
  const float LN2 = 0.69314718055994530942f;
  __shared__ float4 pair4[JSPLIT*CPAD];   // ~16.25 KB planar: (y0,y1,h2_0,h2_1)
  __shared__ float2 pms[JSPLIT][RPB];     // 8 KB: per-chunk (max, sum)

  int bid = blockIdx.x;
  int rc  = bid & 31;          // 32 row-chunks of 64 rows
  int mat = (bid >> 5) & 3;    // 0:f 1:g 2:a 3:b
  int d   = bid >> 7;          // dim
  int t   = threadIdx.x;
  int rs  = t & (RS-1);        // row-slot
  int jc  = t >> 4;            // j-chunk 0..15

  const float* xb = xcol + d*BN;
  const float* yb = ycol + d*BN;
  const float* lw = logw + d*BN;
  const float* ri; const float* pj; int hsel;
  switch (mat){
    case 0:  ri = xb; pj = yb; hsel = 1; break;  // ft: rows x, pts y, dual g
    case 1:  ri = yb; pj = xb; hsel = 0; break;  // gt: rows y, pts x, dual f
    case 2:  ri = xb; pj = xb; hsel = 2; break;  // at
    default: ri = yb; pj = yb; hsel = 3; break;  // bt
  }
  const float* hd  = dold + (size_t)hsel*DN*BN + d*BN;
  const float* dmp = dold + (size_t)mat *DN*BN + d*BN;
  float*       op  = dnew + (size_t)mat *DN*BN + d*BN;

  const float c1 = L2E * inv_eps;          // log2-domain 1/eps
  const float c2 = 0.5f * inv_eps * L2E;   // log2-domain 1/(2 eps)

  // ---- stage (y,y,h2,h2) planar for all 2048 j into LDS (padded chunks) ----
  const float2* pj2 = (const float2*)pj;
  const float2* lw2 = (const float2*)lw;
  const float2* hd2 = (const float2*)hd;
  #pragma unroll
  for (int k = 0; k < SLOTS/TPB; k++){     // 4 iters
    int idx = t + k*TPB;
    int phys = idx + (idx >> 6);           // +1 pad slot per 64
    float2 y2 = pj2[idx];
    float2 l2 = lw2[idx];
    float h0 = l2.x, h1 = l2.y;
    if (mode != 0){
      float2 dd = hd2[idx];
      h0 = fmaf(dd.x, inv_eps, h0);
      h1 = fmaf(dd.y, inv_eps, h1);
    }
    pair4[phys] = make_float4(y2.x, y2.y,
                              fmaf(-c2*y2.x, y2.x, L2E*h0),
                              fmaf(-c2*y2.y, y2.y, L2E*h1));
  }

  int row0 = rc*RPB + rs;
  f2 a2[4];
  #pragma unroll
  for (int r = 0; r < 4; r++){
    float xi = ri[row0 + RS*r];
    float al = c1 * xi;
    a2[r] = (f2){al, al};
  }
  __syncthreads();

  // ---- single sweep: online max + exp-sum, 8-slot read batches ----
  const float4* cb = pair4 + jc*CPAD;      // this chunk's base
  float mrow[4];
  f2 sA[4], sB[4];
  #pragma unroll
  for (int r = 0; r < 4; r++){
    mrow[r] = -INFINITY;
    sA[r] = (f2){0.f, 0.f};
    sB[r] = (f2){0.f, 0.f};
  }
  #pragma unroll 1
  for (int q = 0; q < SPC; q += 8){
    float4 P0 = cb[q+0]; float4 P1 = cb[q+1];
    float4 P2 = cb[q+2]; float4 P3 = cb[q+3];
    float4 P4 = cb[q+4]; float4 P5 = cb[q+5];
    float4 P6 = cb[q+6]; float4 P7 = cb[q+7];
    #pragma unroll
    for (int r = 0; r < 4; r++){
      f2 a = a2[r];
      f2 v0 = __builtin_elementwise_fma(a, (f2){P0.x,P0.y}, (f2){P0.z,P0.w});
      f2 v1 = __builtin_elementwise_fma(a, (f2){P1.x,P1.y}, (f2){P1.z,P1.w});
      f2 v2 = __builtin_elementwise_fma(a, (f2){P2.x,P2.y}, (f2){P2.z,P2.w});
      f2 v3 = __builtin_elementwise_fma(a, (f2){P3.x,P3.y}, (f2){P3.z,P3.w});
      f2 v4 = __builtin_elementwise_fma(a, (f2){P4.x,P4.y}, (f2){P4.z,P4.w});
      f2 v5 = __builtin_elementwise_fma(a, (f2){P5.x,P5.y}, (f2){P5.z,P5.w});
      f2 v6 = __builtin_elementwise_fma(a, (f2){P6.x,P6.y}, (f2){P6.z,P6.w});
      f2 v7 = __builtin_elementwise_fma(a, (f2){P7.x,P7.y}, (f2){P7.z,P7.w});
      // batch max tree
      f2 t0 = __builtin_elementwise_max(v0, v1);
      f2 t1 = __builtin_elementwise_max(v2, v3);
      f2 t2 = __builtin_elementwise_max(v4, v5);
      f2 t3 = __builtin_elementwise_max(v6, v7);
      f2 u0 = __builtin_elementwise_max(t0, t1);
      f2 u1 = __builtin_elementwise_max(t2, t3);
      f2 w  = __builtin_elementwise_max(u0, u1);
      float bm = fmaxf(w.x, w.y);
      float mo = mrow[r];
      float mn = fmaxf(mo, bm);
      float sc = __builtin_amdgcn_exp2f(mo - mn);   // first batch: exp2(-inf)=0
      mrow[r] = mn;
      f2 scv = (f2){sc, sc};
      f2 mv  = (f2){mn, mn};
      f2 x0, x1, x2, x3, x4, x5, x6, x7;
      if (r < 2){  // trans pipe
        x0 = exp2_hw(v0 - mv); x1 = exp2_hw(v1 - mv);
        x2 = exp2_hw(v2 - mv); x3 = exp2_hw(v3 - mv);
        x4 = exp2_hw(v4 - mv); x5 = exp2_hw(v5 - mv);
        x6 = exp2_hw(v6 - mv); x7 = exp2_hw(v7 - mv);
      } else {     // main VALU pipe
        x0 = exp2_poly(v0 - mv); x1 = exp2_poly(v1 - mv);
        x2 = exp2_poly(v2 - mv); x3 = exp2_poly(v3 - mv);
        x4 = exp2_poly(v4 - mv); x5 = exp2_poly(v5 - mv);
        x6 = exp2_poly(v6 - mv); x7 = exp2_poly(v7 - mv);
      }
      // two accumulator chains, rescaled once per batch
      sA[r] = __builtin_elementwise_fma(sA[r], scv, x0);
      sB[r] = __builtin_elementwise_fma(sB[r], scv, x1);
      sA[r] += x2;  sB[r] += x3;
      sA[r] += x4;  sB[r] += x5;
      sA[r] += x6;  sB[r] += x7;
    }
  }
  #pragma unroll
  for (int r = 0; r < 4; r++){
    f2 s = sA[r] + sB[r];
    pms[jc][rs + RS*r] = make_float2(mrow[r], s.x + s.y);
  }
  __syncthreads();

  // ---- cross-chunk merge: M = max m_k; s = sum s_k * 2^(m_k - M) ----
  if (t < RPB){
    int row = rc*RPB + t;
    float M = -INFINITY;
    #pragma unroll
    for (int k = 0; k < JSPLIT; k++) M = fmaxf(M, pms[k][t].x);
    float s = 0.f;
    #pragma unroll
    for (int k = 0; k < JSPLIT; k++){
      float2 p = pms[k][t];
      s = fmaf(p.y, __builtin_amdgcn_exp2f(p.x - M), s);
    }
    float xi = ri[row];
    float beta = c2 * xi * xi;
    float lse2 = (M + __builtin_amdgcn_logf(s)) - beta;   // log2-domain LSE
    float tn = -eps * (LN2 * lse2);
    float outv;
    if (mode == 1 || (mode == 2 && mat >= 2)) outv = 0.5f * (dmp[row] + tn);
    else                                      outv = tn;
    op[row] = outv;
  }
}

__global__ void reduce_kernel(const float* __restrict__ dual, const float* __restrict__ logw,
                              const float* __restrict__ counts, float* __restrict__ out){
  int d = blockIdx.x;
  int t = threadIdx.x;
  int lane = t & 63, wave = t >> 6;
  float acc = 0.f;
  for (int k = 0; k < BN/256; k++){
    int i = t + k*256;
    float w  = expf(logw[d*BN + i]);   // exp(-1e9) -> 0, else 1/n
    float fv = dual[0*DN*BN + d*BN + i];
    float gv = dual[1*DN*BN + d*BN + i];
    float av = dual[2*DN*BN + d*BN + i];
    float bv = dual[3*DN*BN + d*BN + i];
    acc += w * ((fv - av) + (gv - bv));
  }
  __shared__ float sh[4];
  float aw = wave_reduce_sum(acc);
  if (lane == 0) sh[wave] = aw;
  __syncthreads();
  if (t == 0){
    float tot = sh[0] + sh[1] + sh[2] + sh[3];
    out[1 + d] = (counts[d] > 1.5f) ? tot : 0.f;
  }
}

__global__ void total_kernel(float* __restrict__ out){
  if (threadIdx.x == 0 && blockIdx.x == 0){
    float s = 0.f;
    for (int d = 0; d < DN; d++) s += out[1 + d];
    out[0] = s / (float)DN;
  }
}

extern "C" void kernel_launch(void* const* d_in, const int* in_sizes, int n_in,
                              void* d_out, int out_size, void* d_ws, size_t ws_size,
                              hipStream_t stream){
  const float* pred = (const float*)d_in[0];
  const float* targ = (const float*)d_in[1];
  float* out = (float*)d_out;
  float* ws  = (float*)d_ws;

  float* xcol   = ws;
  float* ycol   = ws + (size_t)DN*BN;
  float* logw   = ws + (size_t)2*DN*BN;
  float* counts = ws + (size_t)3*DN*BN;
  float* buf0   = ws + (size_t)3*DN*BN + 64;
  float* buf1   = buf0 + (size_t)4*DN*BN;

  // eps schedule (matches geomloss: diameter^p -> blur^p geometric, ratio scaling^p)
  float eps_list[64]; int n = 0;
  {
    const double P = 2.0, DIAM = 8.0, BLUR = 0.05, SC = 0.9;
    double ls = P*log(DIAM), le = P*log(BLUR), st = P*log(SC);
    eps_list[n++] = (float)pow(DIAM, P);                 // 64
    int cnt = (int)ceil((le - ls)/st);                   // 49
    for (int k = 0; k < cnt; k++) eps_list[n++] = (float)exp(ls + st*(double)k);
    eps_list[n++] = (float)(BLUR*BLUR);                  // 0.0025
  }

  setup_kernel<<<DN, 256, 0, stream>>>(pred, targ, xcol, ycol, logw, counts);

  dim3 grid(DN*4*32), blk(TPB);
  float* cur = buf0; float* nxt = buf1;
  {
    float e = eps_list[0];
    sink_step<<<grid, blk, 0, stream>>>(xcol, ycol, logw, cur, cur, e, 1.f/e, 0);
  }
  for (int k = 0; k < n; k++){
    float e = eps_list[k];
    sink_step<<<grid, blk, 0, stream>>>(xcol, ycol, logw, cur, nxt, e, 1.f/e, 1);
    float* tmp = cur; cur = nxt; nxt = tmp;
  }
  {
    float e = eps_list[n-1];
    sink_step<<<grid, blk, 0, stream>>>(xcol, ycol, logw, cur, nxt, e, 1.f/e, 2);
    float* tmp = cur; cur = nxt; nxt = tmp;
  }
  reduce_kernel<<<DN, 256, 0, stream>>>(cur, logw, counts, out);
  total_kernel<<<1, 64, 0, stream>>>(out);
}

// Round 11
// 1042.084 us; speedup vs baseline: 1.4315x; 1.4315x over previous
//
#include <hip/hip_runtime.h>
#include <math.h>

#define BN 2048
#define DN 8
#define NEGW -1e9f
#define TPB 256            // threads per block (4 waves)
#define RPB 128            // rows per block (each thread owns 8 rows)
#define RS 16              // row-slots (t & 15); rows rs + 16*r, r=0..7
#define JSPLIT 16          // j-chunks; jc = t>>4 (quarter-wave uniform broadcast)
#define SLOTS (BN/2)       // logical float4 slots (2 j per slot)
#define SPC (SLOTS/JSPLIT) // 64 slots = 128 j per chunk
#define CPAD 65            // physical chunk stride in slots (+1 pad)

typedef float f2 __attribute__((ext_vector_type(2)));

static __device__ __forceinline__ float wave_reduce_sum(float v){
  #pragma unroll
  for (int off = 32; off > 0; off >>= 1) v += __shfl_xor(v, off, 64);
  return v;
}
static __device__ __forceinline__ f2 exp2_hw(f2 e){
  return (f2){__builtin_amdgcn_exp2f(e.x), __builtin_amdgcn_exp2f(e.y)};
}

// Transpose inputs into per-dim columns, build masked y, counts, logw.
__global__ void setup_kernel(const float* __restrict__ pred, const float* __restrict__ targ,
                             float* __restrict__ xcol, float* __restrict__ ycol,
                             float* __restrict__ logw, float* __restrict__ counts){
  int d = blockIdx.x;          // 8 blocks
  int t = threadIdx.x;         // 256 threads
  int lane = t & 63, wave = t >> 6;
  float mk[BN/256];
  float c = 0.f;
  for (int k = 0; k < BN/256; k++){
    int i = t + k*256;
    float tv = targ[i*DN + d];
    bool m = !(tv != tv);      // !isnan
    mk[k] = m ? 1.f : 0.f;
    c += mk[k];
    ycol[d*BN + i] = m ? tv : 0.f;
    xcol[d*BN + i] = pred[i*DN + d];
  }
  __shared__ float sh[4];
  __shared__ float logn_sh;
  float cw = wave_reduce_sum(c);
  if (lane == 0) sh[wave] = cw;
  __syncthreads();
  if (t == 0){
    float tot = sh[0] + sh[1] + sh[2] + sh[3];
    counts[d] = tot;
    logn_sh = logf(fmaxf(tot, 1.f));
  }
  __syncthreads();
  float ln = logn_sh;
  for (int k = 0; k < BN/256; k++){
    int i = t + k*256;
    logw[d*BN + i] = (mk[k] > 0.f) ? -ln : NEGW;
  }
}

// One Sinkhorn phase. Round-11: r10's hybrid exp REVERTED (regressed +7.5us/
// step: poly exp = 28 issue-cyc/f2 vs hw v_exp at ~2-4 -> hw exp is near
// full-rate; trans-bound theory refuted). Base = r9's single-sweep online
// softmax (best: 1075us). New: (1) RPB 128 (8 rows/thread, grid 512) halves
// per-CU block-fixed costs (stage+barriers+ramp); (2) H-prefusion: epilogue
// writes H[mat] = logw + dual*inv_eps_next so stage reads 2 streams not 3.
__global__ __launch_bounds__(TPB) void sink_step(
      const float* __restrict__ xcol, const float* __restrict__ ycol,
      const float* __restrict__ logw,
      const float* __restrict__ dold, float* __restrict__ dnew,
      const float* __restrict__ Hold, float* __restrict__ Hnew,
      float eps, float inv_eps, float inv_eps_next, int mode){
  const float L2E = 1.44269504088896340736f;
  const float LN2 = 0.69314718055994530942f;
  __shared__ float4 pair4[JSPLIT*CPAD];   // ~16.25 KB planar: (y0,y1,h2_0,h2_1)
  __shared__ float2 pms[JSPLIT][RPB];     // 16 KB: per-chunk (max, sum)

  int bid = blockIdx.x;
  int rc  = bid & 15;          // 16 row-chunks of 128 rows
  int mat = (bid >> 4) & 3;    // 0:f 1:g 2:a 3:b
  int d   = bid >> 6;          // dim
  int t   = threadIdx.x;
  int rs  = t & (RS-1);        // row-slot
  int jc  = t >> 4;            // j-chunk 0..15

  const float* xb = xcol + d*BN;
  const float* yb = ycol + d*BN;
  const float* lw = logw + d*BN;
  const float* ri; const float* pj; int hsel;
  switch (mat){
    case 0:  ri = xb; pj = yb; hsel = 1; break;  // ft: rows x, pts y, dual g
    case 1:  ri = yb; pj = xb; hsel = 0; break;  // gt: rows y, pts x, dual f
    case 2:  ri = xb; pj = xb; hsel = 2; break;  // at
    default: ri = yb; pj = yb; hsel = 3; break;  // bt
  }
  const float* hp  = Hold + (size_t)hsel*DN*BN + d*BN;  // logw + dual/eps (prefused)
  const float* dmp = dold + (size_t)mat *DN*BN + d*BN;
  float*       op  = dnew + (size_t)mat *DN*BN + d*BN;
  float*       oh  = Hnew + (size_t)mat *DN*BN + d*BN;

  const float c1 = L2E * inv_eps;          // log2-domain 1/eps
  const float c2 = 0.5f * inv_eps * L2E;   // log2-domain 1/(2 eps)

  // ---- stage (y,y,h2,h2) planar for all 2048 j into LDS (padded chunks) ----
  const float2* pj2 = (const float2*)pj;
  const float2* h2src = (mode == 0) ? (const float2*)lw : (const float2*)hp;
  #pragma unroll
  for (int k = 0; k < SLOTS/TPB; k++){     // 4 iters
    int idx = t + k*TPB;
    int phys = idx + (idx >> 6);           // +1 pad slot per 64
    float2 y2 = pj2[idx];
    float2 hh = h2src[idx];
    pair4[phys] = make_float4(y2.x, y2.y,
                              fmaf(-c2*y2.x, y2.x, L2E*hh.x),
                              fmaf(-c2*y2.y, y2.y, L2E*hh.y));
  }

  int row0 = rc*RPB + rs;
  f2 a2[8];
  #pragma unroll
  for (int r = 0; r < 8; r++){
    float xi = ri[row0 + RS*r];
    float al = c1 * xi;
    a2[r] = (f2){al, al};
  }
  __syncthreads();

  // ---- single sweep: online max + exp-sum, 8-slot read batches ----
  const float4* cb = pair4 + jc*CPAD;      // this chunk's base
  float mrow[8];
  f2 sA[8], sB[8];
  #pragma unroll
  for (int r = 0; r < 8; r++){
    mrow[r] = -INFINITY;
    sA[r] = (f2){0.f, 0.f};
    sB[r] = (f2){0.f, 0.f};
  }
  #pragma unroll 1
  for (int q = 0; q < SPC; q += 8){
    float4 P0 = cb[q+0]; float4 P1 = cb[q+1];
    float4 P2 = cb[q+2]; float4 P3 = cb[q+3];
    float4 P4 = cb[q+4]; float4 P5 = cb[q+5];
    float4 P6 = cb[q+6]; float4 P7 = cb[q+7];
    #pragma unroll
    for (int r = 0; r < 8; r++){
      f2 a = a2[r];
      f2 v0 = __builtin_elementwise_fma(a, (f2){P0.x,P0.y}, (f2){P0.z,P0.w});
      f2 v1 = __builtin_elementwise_fma(a, (f2){P1.x,P1.y}, (f2){P1.z,P1.w});
      f2 v2 = __builtin_elementwise_fma(a, (f2){P2.x,P2.y}, (f2){P2.z,P2.w});
      f2 v3 = __builtin_elementwise_fma(a, (f2){P3.x,P3.y}, (f2){P3.z,P3.w});
      f2 v4 = __builtin_elementwise_fma(a, (f2){P4.x,P4.y}, (f2){P4.z,P4.w});
      f2 v5 = __builtin_elementwise_fma(a, (f2){P5.x,P5.y}, (f2){P5.z,P5.w});
      f2 v6 = __builtin_elementwise_fma(a, (f2){P6.x,P6.y}, (f2){P6.z,P6.w});
      f2 v7 = __builtin_elementwise_fma(a, (f2){P7.x,P7.y}, (f2){P7.z,P7.w});
      // batch max tree
      f2 t0 = __builtin_elementwise_max(v0, v1);
      f2 t1 = __builtin_elementwise_max(v2, v3);
      f2 t2 = __builtin_elementwise_max(v4, v5);
      f2 t3 = __builtin_elementwise_max(v6, v7);
      f2 u0 = __builtin_elementwise_max(t0, t1);
      f2 u1 = __builtin_elementwise_max(t2, t3);
      f2 w  = __builtin_elementwise_max(u0, u1);
      float bm = fmaxf(w.x, w.y);
      float mo = mrow[r];
      float mn = fmaxf(mo, bm);
      float sc = __builtin_amdgcn_exp2f(mo - mn);   // first batch: exp2(-inf)=0
      mrow[r] = mn;
      f2 scv = (f2){sc, sc};
      f2 mv  = (f2){mn, mn};
      f2 x0 = exp2_hw(v0 - mv);
      f2 x1 = exp2_hw(v1 - mv);
      f2 x2 = exp2_hw(v2 - mv);
      f2 x3 = exp2_hw(v3 - mv);
      f2 x4 = exp2_hw(v4 - mv);
      f2 x5 = exp2_hw(v5 - mv);
      f2 x6 = exp2_hw(v6 - mv);
      f2 x7 = exp2_hw(v7 - mv);
      // two accumulator chains, rescaled once per batch
      sA[r] = __builtin_elementwise_fma(sA[r], scv, x0);
      sB[r] = __builtin_elementwise_fma(sB[r], scv, x1);
      sA[r] += x2;  sB[r] += x3;
      sA[r] += x4;  sB[r] += x5;
      sA[r] += x6;  sB[r] += x7;
    }
  }
  #pragma unroll
  for (int r = 0; r < 8; r++){
    f2 s = sA[r] + sB[r];
    pms[jc][rs + RS*r] = make_float2(mrow[r], s.x + s.y);
  }
  __syncthreads();

  // ---- cross-chunk merge: M = max m_k; s = sum s_k * 2^(m_k - M) ----
  if (t < RPB){
    int row = rc*RPB + t;
    float M = -INFINITY;
    #pragma unroll
    for (int k = 0; k < JSPLIT; k++) M = fmaxf(M, pms[k][t].x);
    float s = 0.f;
    #pragma unroll
    for (int k = 0; k < JSPLIT; k++){
      float2 p = pms[k][t];
      s = fmaf(p.y, __builtin_amdgcn_exp2f(p.x - M), s);
    }
    float xi = ri[row];
    float beta = c2 * xi * xi;
    float lse2 = (M + __builtin_amdgcn_logf(s)) - beta;   // log2-domain LSE
    float tn = -eps * (LN2 * lse2);
    float outv;
    if (mode == 1 || (mode == 2 && mat >= 2)) outv = 0.5f * (dmp[row] + tn);
    else                                      outv = tn;
    op[row] = outv;
    oh[row] = fmaf(outv, inv_eps_next, lw[row]);  // prefused h for next step
  }
}

__global__ void reduce_kernel(const float* __restrict__ dual, const float* __restrict__ logw,
                              const float* __restrict__ counts, float* __restrict__ out){
  int d = blockIdx.x;
  int t = threadIdx.x;
  int lane = t & 63, wave = t >> 6;
  float acc = 0.f;
  for (int k = 0; k < BN/256; k++){
    int i = t + k*256;
    float w  = expf(logw[d*BN + i]);   // exp(-1e9) -> 0, else 1/n
    float fv = dual[0*DN*BN + d*BN + i];
    float gv = dual[1*DN*BN + d*BN + i];
    float av = dual[2*DN*BN + d*BN + i];
    float bv = dual[3*DN*BN + d*BN + i];
    acc += w * ((fv - av) + (gv - bv));
  }
  __shared__ float sh[4];
  float aw = wave_reduce_sum(acc);
  if (lane == 0) sh[wave] = aw;
  __syncthreads();
  if (t == 0){
    float tot = sh[0] + sh[1] + sh[2] + sh[3];
    out[1 + d] = (counts[d] > 1.5f) ? tot : 0.f;
  }
}

__global__ void total_kernel(float* __restrict__ out){
  if (threadIdx.x == 0 && blockIdx.x == 0){
    float s = 0.f;
    for (int d = 0; d < DN; d++) s += out[1 + d];
    out[0] = s / (float)DN;
  }
}

extern "C" void kernel_launch(void* const* d_in, const int* in_sizes, int n_in,
                              void* d_out, int out_size, void* d_ws, size_t ws_size,
                              hipStream_t stream){
  const float* pred = (const float*)d_in[0];
  const float* targ = (const float*)d_in[1];
  float* out = (float*)d_out;
  float* ws  = (float*)d_ws;

  float* xcol   = ws;
  float* ycol   = ws + (size_t)DN*BN;
  float* logw   = ws + (size_t)2*DN*BN;
  float* counts = ws + (size_t)3*DN*BN;
  float* buf0   = ws + (size_t)3*DN*BN + 64;
  float* buf1   = buf0 + (size_t)4*DN*BN;
  float* H0     = buf1 + (size_t)4*DN*BN;
  float* H1     = H0   + (size_t)4*DN*BN;

  // eps schedule (matches geomloss: diameter^p -> blur^p geometric, ratio scaling^p)
  float eps_list[64]; int n = 0;
  {
    const double P = 2.0, DIAM = 8.0, BLUR = 0.05, SC = 0.9;
    double ls = P*log(DIAM), le = P*log(BLUR), st = P*log(SC);
    eps_list[n++] = (float)pow(DIAM, P);                 // 64
    int cnt = (int)ceil((le - ls)/st);                   // 49
    for (int k = 0; k < cnt; k++) eps_list[n++] = (float)exp(ls + st*(double)k);
    eps_list[n++] = (float)(BLUR*BLUR);                  // 0.0025
  }

  setup_kernel<<<DN, 256, 0, stream>>>(pred, targ, xcol, ycol, logw, counts);

  dim3 grid(DN*4*16), blk(TPB);
  float* cur = buf0;  float* nxt = buf1;
  float* Hc  = H0;    float* Hn  = H1;
  {
    float e = eps_list[0];
    // mode 0: stage reads logw directly; writes cur + Hc (h for step 0's eps)
    sink_step<<<grid, blk, 0, stream>>>(xcol, ycol, logw, cur, cur, Hc, Hc,
                                        e, 1.f/e, 1.f/eps_list[0], 0);
  }
  for (int k = 0; k < n; k++){
    float e = eps_list[k];
    float en = (k+1 < n) ? eps_list[k+1] : eps_list[n-1]; // final extrap uses last eps
    sink_step<<<grid, blk, 0, stream>>>(xcol, ycol, logw, cur, nxt, Hc, Hn,
                                        e, 1.f/e, 1.f/en, 1);
    float* tb = cur; cur = nxt; nxt = tb;
    float* th = Hc;  Hc  = Hn;  Hn  = th;
  }
  {
    float e = eps_list[n-1];
    sink_step<<<grid, blk, 0, stream>>>(xcol, ycol, logw, cur, nxt, Hc, Hn,
                                        e, 1.f/e, 1.f/e, 2);
    float* tb = cur; cur = nxt; nxt = tb;
    float* th = Hc;  Hc  = Hn;  Hn  = th;
  }
  reduce_kernel<<<DN, 256, 0, stream>>>(cur, logw, counts, out);
  total_kernel<<<1, 64, 0, stream>>>(out);
}